// Round 7
// baseline (151.225 us; speedup 1.0000x reference)
//
#include <hip/hip_runtime.h>

#define T_N 1024
#define B_N 512
#define HID 20
#define TB3 (T_N * B_N * 3)   // 1572864
#define MEPAD 1152            // me + 128 zero-pad (kl[d<=0] = 0)

typedef float f4v __attribute__((ext_vector_type(4), aligned(4)));

__device__ __forceinline__ float bcast_lane(float v, int l) {
    return __int_as_float(__builtin_amdgcn_readlane(__float_as_int(v), l));
}

// ---------------- Kernel 1: memory MLP, LDS-staged weights (r6 proven) ----------------
__global__ __launch_bounds__(64) void me_mlp_kernel(
    const float* __restrict__ t,
    const float* __restrict__ w1, const float* __restrict__ b1,
    const float* __restrict__ w2, const float* __restrict__ b2,
    const float* __restrict__ w3, const float* __restrict__ b3,
    const float* __restrict__ w4, const float* __restrict__ b4,
    float* __restrict__ me)
{
    __shared__ float sw2[HID * HID], sw3[HID * HID];
    __shared__ float sw1[HID], sb1[HID], sb2[HID], sb3[HID], sw4[HID];
    __shared__ float sb4;
    const int tx = threadIdx.x;

    for (int i = tx; i < HID * HID; i += 64) { sw2[i] = w2[i]; sw3[i] = w3[i]; }
    for (int i = tx; i < HID; i += 64) {
        sw1[i] = w1[i]; sb1[i] = b1[i]; sb2[i] = b2[i];
        sb3[i] = b3[i]; sw4[i] = w4[i];
    }
    if (tx == 0) sb4 = b4[0];
    __syncthreads();

    const int r = blockIdx.x * 64 + tx;
    if (r >= MEPAD) return;
    if (r >= T_N) { me[r] = 0.0f; return; }

    const float x = t[r];
    float h1[HID], h2[HID], h3[HID];
    #pragma unroll
    for (int k = 0; k < HID; ++k) h1[k] = tanhf(fmaf(x, sw1[k], sb1[k]));
    for (int j = 0; j < HID; ++j) {
        float s = sb2[j];
        #pragma unroll
        for (int k = 0; k < HID; ++k) s = fmaf(h1[k], sw2[k * HID + j], s);
        h2[j] = tanhf(s);
    }
    for (int j = 0; j < HID; ++j) {
        float s = sb3[j];
        #pragma unroll
        for (int k = 0; k < HID; ++k) s = fmaf(h2[k], sw3[k * HID + j], s);
        h3[j] = tanhf(s);
    }
    float o = sb4;
    #pragma unroll
    for (int k = 0; k < HID; ++k) o = fmaf(h3[k], sw4[k], o);
    me[r] = 1.0f / (1.0f + expf(-o));
}

// ---------------- Kernel 2: single-barrier pipeline, W2 carry, LDS-only serial wave ----------------
__global__ __launch_bounds__(256, 2) void ode_kernel(
    const float* __restrict__ t,
    const float* __restrict__ y,
    const float* __restrict__ me,
    const float* __restrict__ betap,
    const float* __restrict__ gammap,
    float* __restrict__ out)
{
    const int b    = blockIdx.x;
    const int tx   = threadIdx.x;
    const int lane = tx & 63;
    const int wv   = tx >> 6;

    __shared__ float Ih[T_N];        // I trajectory
    __shared__ float Sh[T_N];        // S trajectory
    __shared__ float Hs[2][4][64];   // Hmain partials, double-buffered by chunk parity

    const float dt  = t[0] - t[1];   // 1/1024, exact
    const float rdt = 1.0f / dt;
    const float bet = betap[0];
    const float gam = gammap[0];
    const float Af  = dt * bet;
    const float Bf  = 1.0f - dt * gam;
    const float D2  = dt * dt;
    const float kl1 = me[T_N - 1];   // kl[1]

    float S = y[3 * b + 0];
    float I = y[3 * b + 1];
    const float Rc = S + I + y[3 * b + 2];

    Hs[0][wv][lane] = 0.0f;
    if (tx == 0) { Ih[0] = I; Sh[0] = S; }
    if (tx < 3) {
        out[3 * b + tx] = y[3 * b + tx];                        // solution row 0 (exact)
        out[TB3 + (size_t)1023 * B_N * 3 + 3 * b + tx] = 0.0f;  // diff row 1023
    }
    __syncthreads();

    float W2 = 0.0f;   // serial wave: next-chunk accumulator, carried across chunks

    for (int p = 0; p < 16; ++p) {
        const int Js = p * 64;

        if (wv == 0) {
            // ---------- serial: 64 Euler steps; W (this chunk) + W2 (next chunk) ----------
            const int pb = p & 1;
            float W = W2 + (Hs[pb][1][lane] + Hs[pb][2][lane] + Hs[pb][3][lane]);
            W2 = 0.0f;

            const float* gk  = me + (T_N - lane);        // kl[lane-q]    (pad covers q>=lane)
            const float* gk2 = me + (T_N - 64 - lane);   // kl[64+lane-q] (always in-range)
            f4v L[16], L2[16];
            #pragma unroll
            for (int u = 0; u < 16; ++u) {
                L[u]  = *(const f4v*)(gk  + 4 * u);
                L2[u] = *(const f4v*)(gk2 + 4 * u);
            }

            float mS = S, mI = I;
            float pre = bcast_lane(W, 0);

            {   // step 0: W_init is already the complete history sum -> no kl1 fixup
                const float A0 = p ? Af : 0.0f;    // chunk-0 step-0 = initial condition
                const float B0 = p ? Bf : 1.0f;
                const float D0 = p ? D2 : 0.0f;
                const float tot = pre;
                pre = bcast_lane(W, 1);
                const float SI = S * I;
                const float tI = B0 * I;
                const float u1 = fmaf(-A0, SI, S);
                I = fmaf(A0, SI, tI);
                S = fmaf(D0, tot, u1);
                if (lane == 0) { mS = S; mI = I; }
                W  = fmaf(L[0].x,  I, W);
                W2 = fmaf(L2[0].x, I, W2);
            }

#define BSTEP(c, KV, KV2)                                                 \
            {                                                             \
                const float tot = fmaf(kl1, I, pre);                      \
                pre = bcast_lane(W, ((c) + 1) & 63);                      \
                const float SI = S * I;                                   \
                const float tI = Bf * I;                                  \
                const float u1 = fmaf(-Af, SI, S);                        \
                I = fmaf(Af, SI, tI);                                     \
                S = fmaf(D2, tot, u1);                                    \
                if (lane == (c)) { mS = S; mI = I; }                      \
                W  = fmaf((KV),  I, W);                                   \
                W2 = fmaf((KV2), I, W2);                                  \
            }
#define BGRP(U)                                                           \
            BSTEP(4*(U)+0, L[U].x, L2[U].x)                               \
            BSTEP(4*(U)+1, L[U].y, L2[U].y)                               \
            BSTEP(4*(U)+2, L[U].z, L2[U].z)                               \
            BSTEP(4*(U)+3, L[U].w, L2[U].w)

            BSTEP(1, L[0].y, L2[0].y)
            BSTEP(2, L[0].z, L2[0].z)
            BSTEP(3, L[0].w, L2[0].w)
            BGRP(1)  BGRP(2)  BGRP(3)  BGRP(4)  BGRP(5)
            BGRP(6)  BGRP(7)  BGRP(8)  BGRP(9)  BGRP(10)
            BGRP(11) BGRP(12) BGRP(13) BGRP(14) BGRP(15)
#undef BGRP
#undef BSTEP

            Ih[Js + lane] = mI;   // publish chunk p trajectory (LDS only)
            Sh[Js + lane] = mS;
        } else {
            // ---------- stores for chunk p-1 (issued early; drain under this chunk) ----------
            if (p >= 1) {
                const int j = Js - 64 + lane;
                if (wv == 1) {
                    const float s1 = Sh[j], i1 = Ih[j];
                    float* so = out + (size_t)j * (B_N * 3) + 3 * b;
                    so[0] = s1; so[1] = i1; so[2] = Rc - s1 - i1;
                } else if (wv == 2) {
                    if (j >= 1) {
                        const float s1 = Sh[j], i1 = Ih[j];
                        const float s0 = Sh[j - 1], i0 = Ih[j - 1];
                        const float dS = (s1 - s0) * rdt;
                        const float dI = (i1 - i0) * rdt;
                        float* df = out + TB3 + (size_t)(j - 1) * (B_N * 3) + 3 * b;
                        df[0] = dS; df[1] = dI; df[2] = -(dS + dI);
                    }
                }
            }
            // ---------- Hmain for chunk p+1: i < 64p, 3 waves round-robin ----------
            if (p < 15) {
                const int Jt = Js + 64;
                float hm0 = 0.f, hm1 = 0.f, hm2 = 0.f, hm3 = 0.f;
                for (int bb = wv - 1; bb < p; bb += 3) {
                    const int i0 = bb * 64;
                    const float ihv = Ih[i0 + lane];
                    const float* gk = me + (T_N - (Jt - i0) - lane);
                    f4v L[16];
                    #pragma unroll
                    for (int u = 0; u < 16; ++u) L[u] = *(const f4v*)(gk + 4 * u);
                    #pragma unroll
                    for (int g = 0; g < 8; ++g) {
                        const float r0 = bcast_lane(ihv, 8 * g + 0);
                        const float r1 = bcast_lane(ihv, 8 * g + 1);
                        const float r2 = bcast_lane(ihv, 8 * g + 2);
                        const float r3 = bcast_lane(ihv, 8 * g + 3);
                        const float r4 = bcast_lane(ihv, 8 * g + 4);
                        const float r5 = bcast_lane(ihv, 8 * g + 5);
                        const float r6 = bcast_lane(ihv, 8 * g + 6);
                        const float r7 = bcast_lane(ihv, 8 * g + 7);
                        const f4v La = L[2 * g], Lb = L[2 * g + 1];
                        hm0 = fmaf(r0, La.x, hm0);
                        hm1 = fmaf(r1, La.y, hm1);
                        hm2 = fmaf(r2, La.z, hm2);
                        hm3 = fmaf(r3, La.w, hm3);
                        hm0 = fmaf(r4, Lb.x, hm0);
                        hm1 = fmaf(r5, Lb.y, hm1);
                        hm2 = fmaf(r6, Lb.z, hm2);
                        hm3 = fmaf(r7, Lb.w, hm3);
                    }
                }
                Hs[(p + 1) & 1][wv][lane] = (hm0 + hm1) + (hm2 + hm3);
            }
        }
        __syncthreads();   // single barrier per chunk
    }

    // ---------- epilogue: store chunk 15 (rows 960..1023, diff rows 959..1022) ----------
    {
        const int j = 960 + lane;
        if (wv == 1) {
            const float s1 = Sh[j], i1 = Ih[j];
            float* so = out + (size_t)j * (B_N * 3) + 3 * b;
            so[0] = s1; so[1] = i1; so[2] = Rc - s1 - i1;
        } else if (wv == 2) {
            const float s1 = Sh[j], i1 = Ih[j];
            const float s0 = Sh[j - 1], i0 = Ih[j - 1];
            const float dS = (s1 - s0) * rdt;
            const float dI = (i1 - i0) * rdt;
            float* df = out + TB3 + (size_t)(j - 1) * (B_N * 3) + 3 * b;
            df[0] = dS; df[1] = dI; df[2] = -(dS + dI);
        }
    }
}

// ---------------- launcher ----------------
extern "C" void kernel_launch(void* const* d_in, const int* in_sizes, int n_in,
                              void* d_out, int out_size, void* d_ws, size_t ws_size,
                              hipStream_t stream)
{
    const float* t   = (const float*)d_in[0];
    const float* y   = (const float*)d_in[1];
    const float* w1  = (const float*)d_in[2];
    const float* b1  = (const float*)d_in[3];
    const float* w2  = (const float*)d_in[4];
    const float* b2  = (const float*)d_in[5];
    const float* w3  = (const float*)d_in[6];
    const float* b3  = (const float*)d_in[7];
    const float* w4  = (const float*)d_in[8];
    const float* b4  = (const float*)d_in[9];
    const float* bet = (const float*)d_in[10];
    const float* gam = (const float*)d_in[11];
    float* out = (float*)d_out;
    float* me  = (float*)d_ws;   // 1152 floats of scratch (me + zero pad)

    me_mlp_kernel<<<dim3(MEPAD / 64), dim3(64), 0, stream>>>(
        t, w1, b1, w2, b2, w3, b3, w4, b4, me);
    ode_kernel<<<dim3(B_N), dim3(256), 0, stream>>>(t, y, me, bet, gam, out);
}

// Round 8
// 141.716 us; speedup vs baseline: 1.0671x; 1.0671x over previous
//
#include <hip/hip_runtime.h>

#define T_N 1024
#define B_N 512
#define HID 20
#define TB3 (T_N * B_N * 3)   // 1572864
#define MEPAD 1152            // me + 128 zero-pad (kl[d<=0] = 0)

typedef float f4v __attribute__((ext_vector_type(4), aligned(4)));

__device__ __forceinline__ float bcast_lane(float v, int l) {
    return __int_as_float(__builtin_amdgcn_readlane(__float_as_int(v), l));
}

// LDS flag handshake (workgroup scope). Release/acquire give compiler-level
// ordering; backend emits lgkmcnt (and vmcnt on the helper path, where stores
// are already a chunk old) -- crucially NOT coupled across waves like s_barrier.
__device__ __forceinline__ void flag_set(int* f, int v) {
    if ((threadIdx.x & 63) == 0)
        __hip_atomic_store(f, v, __ATOMIC_RELEASE, __HIP_MEMORY_SCOPE_WORKGROUP);
}
__device__ __forceinline__ void flag_wait(int* f, int target) {
    while (__hip_atomic_load(f, __ATOMIC_ACQUIRE, __HIP_MEMORY_SCOPE_WORKGROUP) < target)
        __builtin_amdgcn_s_sleep(2);
}

// ---------------- Kernel 1: memory MLP, LDS-staged weights (r6 proven) ----------------
__global__ __launch_bounds__(64) void me_mlp_kernel(
    const float* __restrict__ t,
    const float* __restrict__ w1, const float* __restrict__ b1,
    const float* __restrict__ w2, const float* __restrict__ b2,
    const float* __restrict__ w3, const float* __restrict__ b3,
    const float* __restrict__ w4, const float* __restrict__ b4,
    float* __restrict__ me)
{
    __shared__ float sw2[HID * HID], sw3[HID * HID];
    __shared__ float sw1[HID], sb1[HID], sb2[HID], sb3[HID], sw4[HID];
    __shared__ float sb4;
    const int tx = threadIdx.x;

    for (int i = tx; i < HID * HID; i += 64) { sw2[i] = w2[i]; sw3[i] = w3[i]; }
    for (int i = tx; i < HID; i += 64) {
        sw1[i] = w1[i]; sb1[i] = b1[i]; sb2[i] = b2[i];
        sb3[i] = b3[i]; sw4[i] = w4[i];
    }
    if (tx == 0) sb4 = b4[0];
    __syncthreads();

    const int r = blockIdx.x * 64 + tx;
    if (r >= MEPAD) return;
    if (r >= T_N) { me[r] = 0.0f; return; }

    const float x = t[r];
    float h1[HID], h2[HID], h3[HID];
    #pragma unroll
    for (int k = 0; k < HID; ++k) h1[k] = tanhf(fmaf(x, sw1[k], sb1[k]));
    for (int j = 0; j < HID; ++j) {
        float s = sb2[j];
        #pragma unroll
        for (int k = 0; k < HID; ++k) s = fmaf(h1[k], sw2[k * HID + j], s);
        h2[j] = tanhf(s);
    }
    for (int j = 0; j < HID; ++j) {
        float s = sb3[j];
        #pragma unroll
        for (int k = 0; k < HID; ++k) s = fmaf(h2[k], sw3[k * HID + j], s);
        h3[j] = tanhf(s);
    }
    float o = sb4;
    #pragma unroll
    for (int k = 0; k < HID; ++k) o = fmaf(h3[k], sw4[k], o);
    me[r] = 1.0f / (1.0f + expf(-o));
}

// ---------------- Kernel 2: barrier-free producer/consumer pipeline ----------------
__global__ __launch_bounds__(256, 2) void ode_kernel(
    const float* __restrict__ t,
    const float* __restrict__ y,
    const float* __restrict__ me,
    const float* __restrict__ betap,
    const float* __restrict__ gammap,
    float* __restrict__ out)
{
    const int b    = blockIdx.x;
    const int tx   = threadIdx.x;
    const int lane = tx & 63;
    const int wv   = tx >> 6;

    __shared__ float Ih[T_N];        // I trajectory
    __shared__ float Sh[T_N];        // S trajectory
    __shared__ float Hs[2][3][64];   // helper Hmain slices, parity double-buffered
    __shared__ int   flagI;          // serial -> helpers: chunks published
    __shared__ int   flagH[4];       // helpers -> serial: Hmain ready through chunk

    const float dt  = t[0] - t[1];   // 1/1024, exact
    const float rdt = 1.0f / dt;
    const float bet = betap[0];
    const float gam = gammap[0];
    const float Af  = dt * bet;
    const float Bf  = 1.0f - dt * gam;
    const float D2  = dt * dt;
    const float kl1 = me[T_N - 1];   // kl[1]

    float S = y[3 * b + 0];
    float I = y[3 * b + 1];
    const float Rc = S + I + y[3 * b + 2];

    if (wv == 0) { Hs[0][0][lane] = 0.f; Hs[0][1][lane] = 0.f; Hs[0][2][lane] = 0.f; }
    if (tx == 0) { Ih[0] = I; Sh[0] = S; flagI = 0; flagH[1] = flagH[2] = flagH[3] = 0; }
    if (tx < 3) {
        out[3 * b + tx] = y[3 * b + tx];                        // solution row 0
        out[TB3 + (size_t)1023 * B_N * 3 + 3 * b + tx] = 0.0f;  // diff row 1023
    }
    __syncthreads();   // one-time init barrier (nothing in flight)

    if (wv == 0) {
        // ================= SERIAL WAVE =================
        float W2 = 0.0f;
        for (int p = 0; p < 16; ++p) {
            const int Js = p * 64;
            if (p) {
                flag_wait(&flagH[1], p);
                flag_wait(&flagH[2], p);
                flag_wait(&flagH[3], p);
            }
            const int pb = p & 1;
            float W = W2 + (Hs[pb][0][lane] + Hs[pb][1][lane] + Hs[pb][2][lane]);
            W2 = 0.0f;

            const float* gk  = me + (T_N - lane);        // kl[lane-q]
            const float* gk2 = me + (T_N - 64 - lane);   // kl[64+lane-q]
            f4v L[16], L2[16];
            #pragma unroll
            for (int u = 0; u < 16; ++u) {
                L[u]  = *(const f4v*)(gk  + 4 * u);
                L2[u] = *(const f4v*)(gk2 + 4 * u);
            }

            float mS = S, mI = I;
            float pre = bcast_lane(W, 0);

            {   // step 0 (chunk 0: initial condition)
                const float A0 = p ? Af : 0.0f;
                const float B0 = p ? Bf : 1.0f;
                const float D0 = p ? D2 : 0.0f;
                const float tot = pre;
                pre = bcast_lane(W, 1);
                const float SI = S * I;
                const float tI = B0 * I;
                const float u1 = fmaf(-A0, SI, S);
                I = fmaf(A0, SI, tI);
                S = fmaf(D0, tot, u1);
                if (lane == 0) { mS = S; mI = I; }
                W  = fmaf(L[0].x,  I, W);
                W2 = fmaf(L2[0].x, I, W2);
            }

#define BSTEP(c, KV, KV2)                                                 \
            {                                                             \
                const float tot = fmaf(kl1, I, pre);                      \
                pre = bcast_lane(W, ((c) + 1) & 63);                      \
                const float SI = S * I;                                   \
                const float tI = Bf * I;                                  \
                const float u1 = fmaf(-Af, SI, S);                        \
                I = fmaf(Af, SI, tI);                                     \
                S = fmaf(D2, tot, u1);                                    \
                if (lane == (c)) { mS = S; mI = I; }                      \
                W  = fmaf((KV),  I, W);                                   \
                W2 = fmaf((KV2), I, W2);                                  \
            }
#define BGRP(U)                                                           \
            BSTEP(4*(U)+0, L[U].x, L2[U].x)                               \
            BSTEP(4*(U)+1, L[U].y, L2[U].y)                               \
            BSTEP(4*(U)+2, L[U].z, L2[U].z)                               \
            BSTEP(4*(U)+3, L[U].w, L2[U].w)

            BSTEP(1, L[0].y, L2[0].y)
            BSTEP(2, L[0].z, L2[0].z)
            BSTEP(3, L[0].w, L2[0].w)
            BGRP(1)  BGRP(2)  BGRP(3)  BGRP(4)  BGRP(5)
            BGRP(6)  BGRP(7)  BGRP(8)  BGRP(9)  BGRP(10)
            BGRP(11) BGRP(12) BGRP(13) BGRP(14) BGRP(15)
#undef BGRP
#undef BSTEP

            Ih[Js + lane] = mI;
            Sh[Js + lane] = mS;
            flag_set(&flagI, p + 1);   // release: publishes Ih/Sh chunk p
        }
    } else {
        // ================= HELPER WAVES (wv 1..3) =================
        for (int p = 0; p < 16; ++p) {
            const int Js = p * 64;
            if (p >= 1) {
                flag_wait(&flagI, p);   // chunks 0..p-1 published
                // ---- stores of chunk p-1 (fire-and-forget) ----
                const int j = Js - 64 + lane;
                if (wv == 1) {
                    const float s1 = Sh[j], i1 = Ih[j];
                    float* so = out + (size_t)j * (B_N * 3) + 3 * b;
                    so[0] = s1; so[1] = i1; so[2] = Rc - s1 - i1;
                } else if (wv == 2 && j >= 1) {
                    const float s1 = Sh[j], i1 = Ih[j];
                    const float s0 = Sh[j - 1], i0 = Ih[j - 1];
                    const float dS = (s1 - s0) * rdt;
                    const float dI = (i1 - i0) * rdt;
                    float* df = out + TB3 + (size_t)(j - 1) * (B_N * 3) + 3 * b;
                    df[0] = dS; df[1] = dI; df[2] = -(dS + dI);
                }
            }
            // ---- Hmain(p+1): i < 64p, 3-wave round-robin ----
            if (p < 15) {
                const int Jt = Js + 64;
                float hm0 = 0.f, hm1 = 0.f, hm2 = 0.f, hm3 = 0.f;
                for (int bb = wv - 1; bb < p; bb += 3) {
                    const int i0 = bb * 64;
                    const float ihv = Ih[i0 + lane];
                    const float* gk = me + (T_N - (Jt - i0) - lane);
                    f4v L[16];
                    #pragma unroll
                    for (int u = 0; u < 16; ++u) L[u] = *(const f4v*)(gk + 4 * u);
                    #pragma unroll
                    for (int g = 0; g < 8; ++g) {
                        const float r0 = bcast_lane(ihv, 8 * g + 0);
                        const float r1 = bcast_lane(ihv, 8 * g + 1);
                        const float r2 = bcast_lane(ihv, 8 * g + 2);
                        const float r3 = bcast_lane(ihv, 8 * g + 3);
                        const float r4 = bcast_lane(ihv, 8 * g + 4);
                        const float r5 = bcast_lane(ihv, 8 * g + 5);
                        const float r6 = bcast_lane(ihv, 8 * g + 6);
                        const float r7 = bcast_lane(ihv, 8 * g + 7);
                        const f4v La = L[2 * g], Lb = L[2 * g + 1];
                        hm0 = fmaf(r0, La.x, hm0);
                        hm1 = fmaf(r1, La.y, hm1);
                        hm2 = fmaf(r2, La.z, hm2);
                        hm3 = fmaf(r3, La.w, hm3);
                        hm0 = fmaf(r4, Lb.x, hm0);
                        hm1 = fmaf(r5, Lb.y, hm1);
                        hm2 = fmaf(r6, Lb.z, hm2);
                        hm3 = fmaf(r7, Lb.w, hm3);
                    }
                }
                Hs[(p + 1) & 1][wv - 1][lane] = (hm0 + hm1) + (hm2 + hm3);
                flag_set(&flagH[wv], p + 1);   // release: Hs slice ready
            }
        }
        // ---- epilogue: chunk 15 rows ----
        if (wv == 1 || wv == 2) {
            flag_wait(&flagI, 16);
            const int j = 960 + lane;
            if (wv == 1) {
                const float s1 = Sh[j], i1 = Ih[j];
                float* so = out + (size_t)j * (B_N * 3) + 3 * b;
                so[0] = s1; so[1] = i1; so[2] = Rc - s1 - i1;
            } else {
                const float s1 = Sh[j], i1 = Ih[j];
                const float s0 = Sh[j - 1], i0 = Ih[j - 1];
                const float dS = (s1 - s0) * rdt;
                const float dI = (i1 - i0) * rdt;
                float* df = out + TB3 + (size_t)(j - 1) * (B_N * 3) + 3 * b;
                df[0] = dS; df[1] = dI; df[2] = -(dS + dI);
            }
        }
    }
}

// ---------------- launcher ----------------
extern "C" void kernel_launch(void* const* d_in, const int* in_sizes, int n_in,
                              void* d_out, int out_size, void* d_ws, size_t ws_size,
                              hipStream_t stream)
{
    const float* t   = (const float*)d_in[0];
    const float* y   = (const float*)d_in[1];
    const float* w1  = (const float*)d_in[2];
    const float* b1  = (const float*)d_in[3];
    const float* w2  = (const float*)d_in[4];
    const float* b2  = (const float*)d_in[5];
    const float* w3  = (const float*)d_in[6];
    const float* b3  = (const float*)d_in[7];
    const float* w4  = (const float*)d_in[8];
    const float* b4  = (const float*)d_in[9];
    const float* bet = (const float*)d_in[10];
    const float* gam = (const float*)d_in[11];
    float* out = (float*)d_out;
    float* me  = (float*)d_ws;   // 1152 floats of scratch (me + zero pad)

    me_mlp_kernel<<<dim3(MEPAD / 64), dim3(64), 0, stream>>>(
        t, w1, b1, w2, b2, w3, b3, w4, b4, me);
    ode_kernel<<<dim3(B_N), dim3(256), 0, stream>>>(t, y, me, bet, gam, out);
}